// Round 5
// baseline (171.946 us; speedup 1.0000x reference)
//
#include <hip/hip_runtime.h>
#include <math.h>

#define BATCHES 128
#define T_LEN   32768
#define S_DIM   4
#define CHUNKS  16
#define BLOCK   256
#define NACC    21                            // D[16] + L1[4] + msum
#define LN2F    0.69314718055994530942f

// Hardware log2 (v_log_f32). Inputs are clipped to [1e-7, 1-1e-7] -> no edge cases.
__device__ __forceinline__ float hw_log2(float x) { return __builtin_amdgcn_logf(x); }

// Accumulate two timesteps (all indexing static after inline+unroll).
__device__ __forceinline__ void accum2(
    const float4 pv0, const float4 tv0, const float m0,
    const float4 pv1, const float4 tv1, const float m1,
    float D[4][4], float L1[4], float& msum)
{
    const float pa0[4] = {pv0.x, pv0.y, pv0.z, pv0.w};
    const float ta0[4] = {tv0.x, tv0.y, tv0.z, tv0.w};
    const float pa1[4] = {pv1.x, pv1.y, pv1.z, pv1.w};
    const float ta1[4] = {tv1.x, tv1.y, tv1.z, tv1.w};

    float md0[4], md1[4];
    #pragma unroll
    for (int i = 0; i < 4; ++i) {
        const float p0   = fminf(fmaxf(pa0[i], 1e-7f), 1.0f - 1e-7f);
        const float p1   = fminf(fmaxf(pa1[i], 1e-7f), 1.0f - 1e-7f);
        const float lp0  = hw_log2(p0);
        const float lp1  = hw_log2(p1);
        const float l1p0 = hw_log2(1.0f - p0);   // 1-p exact for p>=0.5 (Sterbenz)
        const float l1p1 = hw_log2(1.0f - p1);
        md0[i] = m0 * (lp0 - l1p0);              // m * logit (log2 domain)
        md1[i] = m1 * (lp1 - l1p1);
        L1[i]  = fmaf(m0, l1p0, L1[i]);
        L1[i]  = fmaf(m1, l1p1, L1[i]);
    }
    #pragma unroll
    for (int i = 0; i < 4; ++i)
        #pragma unroll
        for (int j = 0; j < 4; ++j) {
            D[i][j] = fmaf(md0[i], ta0[j], D[i][j]);
            D[i][j] = fmaf(md1[i], ta1[j], D[i][j]);
        }
    msum += m0 + m1;
}

// Kernel 1: per-(batch,chunk) partial sums in log2 domain.
// Software-pipelined depth-2, 2 timesteps per stage -> 6 independent loads
// in flight per wave while the previous stage computes.
__global__ __launch_bounds__(BLOCK) void pit_partial_kernel(
    const float* __restrict__ pred,
    const float* __restrict__ target,
    const float* __restrict__ mask,
    float* __restrict__ partial)   // [BATCHES][CHUNKS][NACC]
{
    const int b     = blockIdx.x / CHUNKS;
    const int chunk = blockIdx.x % CHUNKS;
    const int tid   = threadIdx.x;

    const float4* __restrict__ predv = (const float4*)(pred   + (size_t)b * T_LEN * S_DIM);
    const float4* __restrict__ targv = (const float4*)(target + (size_t)b * T_LEN * S_DIM);
    const float*  __restrict__ maskb = mask + (size_t)b * T_LEN;

    const int t0 = chunk * (T_LEN / CHUNKS) + tid;   // 8 t's per thread, stride BLOCK

    float D[4][4] = {{0.f,0.f,0.f,0.f},{0.f,0.f,0.f,0.f},
                     {0.f,0.f,0.f,0.f},{0.f,0.f,0.f,0.f}};
    float L1[4]   = {0.f,0.f,0.f,0.f};
    float msum    = 0.f;

    // Named stage buffers (rule #20: no runtime-indexed register arrays).
    float4 Ap0, Ap1, At0, At1; float Am0, Am1;
    float4 Bp0, Bp1, Bt0, Bt1; float Bm0, Bm1;

#define LD_A(it)                                            \
    Ap0 = predv[t0 + ((it)*2 + 0) * BLOCK];                 \
    Ap1 = predv[t0 + ((it)*2 + 1) * BLOCK];                 \
    At0 = targv[t0 + ((it)*2 + 0) * BLOCK];                 \
    At1 = targv[t0 + ((it)*2 + 1) * BLOCK];                 \
    Am0 = maskb[t0 + ((it)*2 + 0) * BLOCK];                 \
    Am1 = maskb[t0 + ((it)*2 + 1) * BLOCK];
#define LD_B(it)                                            \
    Bp0 = predv[t0 + ((it)*2 + 0) * BLOCK];                 \
    Bp1 = predv[t0 + ((it)*2 + 1) * BLOCK];                 \
    Bt0 = targv[t0 + ((it)*2 + 0) * BLOCK];                 \
    Bt1 = targv[t0 + ((it)*2 + 1) * BLOCK];                 \
    Bm0 = maskb[t0 + ((it)*2 + 0) * BLOCK];                 \
    Bm1 = maskb[t0 + ((it)*2 + 1) * BLOCK];

    // 4 stages of 2 timesteps = 8 t's per thread; depth-2 pipeline.
    LD_A(0);
    LD_B(1);
    accum2(Ap0, At0, Am0, Ap1, At1, Am1, D, L1, msum);  LD_A(2);
    accum2(Bp0, Bt0, Bm0, Bp1, Bt1, Bm1, D, L1, msum);  LD_B(3);
    accum2(Ap0, At0, Am0, Ap1, At1, Am1, D, L1, msum);
    accum2(Bp0, Bt0, Bm0, Bp1, Bt1, Bm1, D, L1, msum);

#undef LD_A
#undef LD_B

    // Pack accumulators (static indexing throughout — full unroll).
    float acc[NACC];
    #pragma unroll
    for (int i = 0; i < 4; ++i)
        #pragma unroll
        for (int j = 0; j < 4; ++j)
            acc[i * 4 + j] = D[i][j];
    #pragma unroll
    for (int i = 0; i < 4; ++i) acc[16 + i] = L1[i];
    acc[20] = msum;

    // Wave-64 shuffle reduction.
    #pragma unroll
    for (int k = 0; k < NACC; ++k) {
        float v = acc[k];
        #pragma unroll
        for (int off = 32; off >= 1; off >>= 1)
            v += __shfl_down(v, off, 64);
        acc[k] = v;
    }

    __shared__ float red[4][NACC];
    const int wave = tid >> 6;
    const int lane = tid & 63;
    if (lane == 0) {
        #pragma unroll
        for (int k = 0; k < NACC; ++k) red[wave][k] = acc[k];
    }
    __syncthreads();
    if (tid == 0) {
        float* __restrict__ dst = partial + ((size_t)b * CHUNKS + chunk) * NACC;
        #pragma unroll
        for (int k = 0; k < NACC; ++k)
            dst[k] = red[0][k] + red[1][k] + red[2][k] + red[3][k];
    }
}

// Kernel 2: one thread per batch — sum chunk partials, 24-perm max, mean.
__global__ __launch_bounds__(128) void pit_final_kernel(
    const float* __restrict__ partial,
    float* __restrict__ out)
{
    const int b = threadIdx.x;   // exactly BATCHES threads

    float acc[NACC];
    #pragma unroll
    for (int k = 0; k < NACC; ++k) acc[k] = 0.f;

    for (int c = 0; c < CHUNKS; ++c) {
        const float* __restrict__ src = partial + ((size_t)b * CHUNKS + c) * NACC;
        #pragma unroll
        for (int k = 0; k < NACC; ++k) acc[k] += src[k];
    }

    const float sumL1 = acc[16] + acc[17] + acc[18] + acc[19];
    const float msum  = acc[20];

    // max over all 24 permutations of sum_i D[i, perm[i]]  (log2 domain;
    // positive scaling by ln2 preserves the argmax)
    float best = -3.4e38f;
    #pragma unroll
    for (int i0 = 0; i0 < 4; ++i0) {
        #pragma unroll
        for (int i1 = 0; i1 < 4; ++i1) {
            if (i1 == i0) continue;
            #pragma unroll
            for (int i2 = 0; i2 < 4; ++i2) {
                if (i2 == i0 || i2 == i1) continue;
                const int i3 = 6 - i0 - i1 - i2;
                const float s = acc[0 * 4 + i0] + acc[1 * 4 + i1] +
                                acc[2 * 4 + i2] + acc[3 * 4 + i3];
                best = fmaxf(best, s);
            }
        }
    }

    // Convert log2-domain sums to natural-log domain with a single multiply.
    const float min_tot = -LN2F * (best + sumL1) / msum;          // min over perms of tot
    float contrib = min_tot * (1.0f / (S_DIM * BATCHES));         // /S then mean over B

    // Block reduce across 128 threads (2 waves).
    #pragma unroll
    for (int off = 32; off >= 1; off >>= 1)
        contrib += __shfl_down(contrib, off, 64);

    __shared__ float wsum[2];
    const int wave = threadIdx.x >> 6;
    const int lane = threadIdx.x & 63;
    if (lane == 0) wsum[wave] = contrib;
    __syncthreads();
    if (threadIdx.x == 0) out[0] = wsum[0] + wsum[1];
}

extern "C" void kernel_launch(void* const* d_in, const int* in_sizes, int n_in,
                              void* d_out, int out_size, void* d_ws, size_t ws_size,
                              hipStream_t stream) {
    const float* pred   = (const float*)d_in[0];
    const float* target = (const float*)d_in[1];
    const float* mask   = (const float*)d_in[2];
    float* out     = (float*)d_out;
    float* partial = (float*)d_ws;   // fully overwritten each launch; no memset needed

    pit_partial_kernel<<<BATCHES * CHUNKS, BLOCK, 0, stream>>>(pred, target, mask, partial);
    pit_final_kernel<<<1, 128, 0, stream>>>(partial, out);
}

// Round 6
// 170.159 us; speedup vs baseline: 1.0105x; 1.0105x over previous
//
#include <hip/hip_runtime.h>
#include <math.h>

#define BATCHES 128
#define T_LEN   32768
#define S_DIM   4
#define CHUNKS  16
#define BLOCK   256
#define NACC    21                            // D[16] + L1[4] + msum
#define LN2F    0.69314718055994530942f

// Hardware log2 (v_log_f32). Inputs are clipped to [1e-7, 1-1e-7] -> no edge cases.
__device__ __forceinline__ float hw_log2(float x) { return __builtin_amdgcn_logf(x); }

// Accumulate one timestep (all indexing static after inline+unroll).
__device__ __forceinline__ void accum1(
    const float4 pv, const float4 tv, const float m,
    float D[4][4], float L1[4], float& msum)
{
    const float pa[4] = {pv.x, pv.y, pv.z, pv.w};
    const float ta[4] = {tv.x, tv.y, tv.z, tv.w};
    float md[4];
    #pragma unroll
    for (int i = 0; i < 4; ++i) {
        const float p   = fminf(fmaxf(pa[i], 1e-7f), 1.0f - 1e-7f);
        const float lp  = hw_log2(p);            // log2(p)
        const float l1p = hw_log2(1.0f - p);     // 1-p exact for p>=0.5 (Sterbenz)
        md[i] = m * (lp - l1p);                  // m * logit (log2 domain)
        L1[i] = fmaf(m, l1p, L1[i]);
    }
    #pragma unroll
    for (int i = 0; i < 4; ++i)
        #pragma unroll
        for (int j = 0; j < 4; ++j)
            D[i][j] = fmaf(md[i], ta[j], D[i][j]);
    msum += m;
}

// Kernel 1: per-(batch,chunk) partial sums in log2 domain.
// ALL 24 loads (8 t's x {pred4,targ4,mask}) are issued up front into named
// registers, then sched_barrier(0) pins them above the compute so the
// scheduler cannot sink them back to first-use (which is what erased the
// Round-4 pipeline: VGPR stayed 40). ~110 VGPR budgeted via launch_bounds.
__global__ __launch_bounds__(BLOCK, 4) void pit_partial_kernel(
    const float* __restrict__ pred,
    const float* __restrict__ target,
    const float* __restrict__ mask,
    float* __restrict__ partial)   // [BATCHES][CHUNKS][NACC]
{
    const int b     = blockIdx.x / CHUNKS;
    const int chunk = blockIdx.x % CHUNKS;
    const int tid   = threadIdx.x;

    const float4* __restrict__ predv = (const float4*)(pred   + (size_t)b * T_LEN * S_DIM);
    const float4* __restrict__ targv = (const float4*)(target + (size_t)b * T_LEN * S_DIM);
    const float*  __restrict__ maskb = mask + (size_t)b * T_LEN;

    const int t0 = chunk * (T_LEN / CHUNKS) + tid;   // 8 t's per thread, stride BLOCK

    // ---- Issue ALL loads first (24 VMEM instructions in flight per wave) ----
    float4 P0, P1, P2, P3, P4, P5, P6, P7;
    float4 T0, T1, T2, T3, T4, T5, T6, T7;
    float  M0, M1, M2, M3, M4, M5, M6, M7;

    P0 = predv[t0 + 0 * BLOCK]; T0 = targv[t0 + 0 * BLOCK]; M0 = maskb[t0 + 0 * BLOCK];
    P1 = predv[t0 + 1 * BLOCK]; T1 = targv[t0 + 1 * BLOCK]; M1 = maskb[t0 + 1 * BLOCK];
    P2 = predv[t0 + 2 * BLOCK]; T2 = targv[t0 + 2 * BLOCK]; M2 = maskb[t0 + 2 * BLOCK];
    P3 = predv[t0 + 3 * BLOCK]; T3 = targv[t0 + 3 * BLOCK]; M3 = maskb[t0 + 3 * BLOCK];
    P4 = predv[t0 + 4 * BLOCK]; T4 = targv[t0 + 4 * BLOCK]; M4 = maskb[t0 + 4 * BLOCK];
    P5 = predv[t0 + 5 * BLOCK]; T5 = targv[t0 + 5 * BLOCK]; M5 = maskb[t0 + 5 * BLOCK];
    P6 = predv[t0 + 6 * BLOCK]; T6 = targv[t0 + 6 * BLOCK]; M6 = maskb[t0 + 6 * BLOCK];
    P7 = predv[t0 + 7 * BLOCK]; T7 = targv[t0 + 7 * BLOCK]; M7 = maskb[t0 + 7 * BLOCK];

    // Pin: no compute may be scheduled above, no load sunk below.
    __builtin_amdgcn_sched_barrier(0);

    float D[4][4] = {{0.f,0.f,0.f,0.f},{0.f,0.f,0.f,0.f},
                     {0.f,0.f,0.f,0.f},{0.f,0.f,0.f,0.f}};
    float L1[4]   = {0.f,0.f,0.f,0.f};
    float msum    = 0.f;

    accum1(P0, T0, M0, D, L1, msum);
    accum1(P1, T1, M1, D, L1, msum);
    accum1(P2, T2, M2, D, L1, msum);
    accum1(P3, T3, M3, D, L1, msum);
    accum1(P4, T4, M4, D, L1, msum);
    accum1(P5, T5, M5, D, L1, msum);
    accum1(P6, T6, M6, D, L1, msum);
    accum1(P7, T7, M7, D, L1, msum);

    // Pack accumulators (static indexing throughout — full unroll).
    float acc[NACC];
    #pragma unroll
    for (int i = 0; i < 4; ++i)
        #pragma unroll
        for (int j = 0; j < 4; ++j)
            acc[i * 4 + j] = D[i][j];
    #pragma unroll
    for (int i = 0; i < 4; ++i) acc[16 + i] = L1[i];
    acc[20] = msum;

    // Wave-64 shuffle reduction.
    #pragma unroll
    for (int k = 0; k < NACC; ++k) {
        float v = acc[k];
        #pragma unroll
        for (int off = 32; off >= 1; off >>= 1)
            v += __shfl_down(v, off, 64);
        acc[k] = v;
    }

    __shared__ float red[4][NACC];
    const int wave = tid >> 6;
    const int lane = tid & 63;
    if (lane == 0) {
        #pragma unroll
        for (int k = 0; k < NACC; ++k) red[wave][k] = acc[k];
    }
    __syncthreads();
    if (tid == 0) {
        float* __restrict__ dst = partial + ((size_t)b * CHUNKS + chunk) * NACC;
        #pragma unroll
        for (int k = 0; k < NACC; ++k)
            dst[k] = red[0][k] + red[1][k] + red[2][k] + red[3][k];
    }
}

// Kernel 2: one thread per batch — sum chunk partials, 24-perm max, mean.
__global__ __launch_bounds__(128) void pit_final_kernel(
    const float* __restrict__ partial,
    float* __restrict__ out)
{
    const int b = threadIdx.x;   // exactly BATCHES threads

    float acc[NACC];
    #pragma unroll
    for (int k = 0; k < NACC; ++k) acc[k] = 0.f;

    for (int c = 0; c < CHUNKS; ++c) {
        const float* __restrict__ src = partial + ((size_t)b * CHUNKS + c) * NACC;
        #pragma unroll
        for (int k = 0; k < NACC; ++k) acc[k] += src[k];
    }

    const float sumL1 = acc[16] + acc[17] + acc[18] + acc[19];
    const float msum  = acc[20];

    // max over all 24 permutations of sum_i D[i, perm[i]]  (log2 domain;
    // positive scaling by ln2 preserves the argmax)
    float best = -3.4e38f;
    #pragma unroll
    for (int i0 = 0; i0 < 4; ++i0) {
        #pragma unroll
        for (int i1 = 0; i1 < 4; ++i1) {
            if (i1 == i0) continue;
            #pragma unroll
            for (int i2 = 0; i2 < 4; ++i2) {
                if (i2 == i0 || i2 == i1) continue;
                const int i3 = 6 - i0 - i1 - i2;
                const float s = acc[0 * 4 + i0] + acc[1 * 4 + i1] +
                                acc[2 * 4 + i2] + acc[3 * 4 + i3];
                best = fmaxf(best, s);
            }
        }
    }

    // Convert log2-domain sums to natural-log domain with a single multiply.
    const float min_tot = -LN2F * (best + sumL1) / msum;          // min over perms of tot
    float contrib = min_tot * (1.0f / (S_DIM * BATCHES));         // /S then mean over B

    // Block reduce across 128 threads (2 waves).
    #pragma unroll
    for (int off = 32; off >= 1; off >>= 1)
        contrib += __shfl_down(contrib, off, 64);

    __shared__ float wsum[2];
    const int wave = threadIdx.x >> 6;
    const int lane = threadIdx.x & 63;
    if (lane == 0) wsum[wave] = contrib;
    __syncthreads();
    if (threadIdx.x == 0) out[0] = wsum[0] + wsum[1];
}

extern "C" void kernel_launch(void* const* d_in, const int* in_sizes, int n_in,
                              void* d_out, int out_size, void* d_ws, size_t ws_size,
                              hipStream_t stream) {
    const float* pred   = (const float*)d_in[0];
    const float* target = (const float*)d_in[1];
    const float* mask   = (const float*)d_in[2];
    float* out     = (float*)d_out;
    float* partial = (float*)d_ws;   // fully overwritten each launch; no memset needed

    pit_partial_kernel<<<BATCHES * CHUNKS, BLOCK, 0, stream>>>(pred, target, mask, partial);
    pit_final_kernel<<<1, 128, 0, stream>>>(partial, out);
}